// Round 3
// baseline (319.179 us; speedup 1.0000x reference)
//
#include <hip/hip_runtime.h>
#include <hip/hip_bf16.h>

#define B_ROWS 4096
#define D_DIM  512
#define N_ROWS 8192
#define INV_T  20.0f
#define EPS_N  1e-8f
#define CSPLIT 8
#define BM 128                                  // rows per block
#define BN 128                                  // cols per strip
#define KSTEP 64
#define COLS_PER_CHUNK (N_ROWS / CSPLIT)        // 1024
#define STRIPS (COLS_PER_CHUNK / BN)            // 8
#define KSTEPS (D_DIM / KSTEP)                  // 8
#define NIT (STRIPS * KSTEPS)                   // 64

typedef __attribute__((ext_vector_type(8))) short short8;
typedef __attribute__((ext_vector_type(4))) float floatx4;

// swizzled LDS frag read: tile row-major [rows][64] bf16 (128 B/row), byte ^= (row&7)<<4
__device__ __forceinline__ short8 ldsFrag(const char* base, int row, int kbyte) {
  int off = (row * 128 + kbyte) ^ ((row & 7) << 4);
  return *(const short8*)(base + off);
}

__device__ __forceinline__ void insert5(float (&t)[5], float v) {
  #pragma unroll
  for (int i = 0; i < 5; ++i) {
    float hi = fmaxf(t[i], v);
    float lo = fminf(t[i], v);
    t[i] = hi;
    v = lo;
  }
}

__device__ __forceinline__ void scan_acc(floatx4 (&acc)[4][4], float (&sum)[4],
                                         float (&top)[4][5], const int (&myrow)[4],
                                         int scanbase) {
  #pragma unroll
  for (int j = 0; j < 4; ++j) {
    #pragma unroll
    for (int i = 0; i < 4; ++i) {
      #pragma unroll
      for (int e = 0; e < 4; ++e) {
        int col = scanbase + i * 16 + e;
        float ev = __expf(acc[i][j][e] * INV_T);
        ev = (col == myrow[j]) ? 0.0f : ev;
        sum[j] += ev;
        insert5(top[j], ev);
      }
    }
  }
}

// -------------------- kernel 1: normalize -> bf16, dot(f1,f2) --------------------
__global__ __launch_bounds__(256) void prep_kernel(
    const float* __restrict__ f1, const float* __restrict__ f2,
    __hip_bfloat16* __restrict__ fnb, float* __restrict__ dots)
{
  int row = blockIdx.x;          // 0..4095
  int t = threadIdx.x;           // 256 threads, 2 elems each
  const float* r1 = f1 + (size_t)row * D_DIM;
  const float* r2 = f2 + (size_t)row * D_DIM;
  float2 a = *(const float2*)(r1 + 2 * t);
  float2 b = *(const float2*)(r2 + 2 * t);
  float s1 = a.x * a.x + a.y * a.y;
  float s2 = b.x * b.x + b.y * b.y;
  float d  = a.x * b.x + a.y * b.y;
  #pragma unroll
  for (int off = 32; off >= 1; off >>= 1) {
    s1 += __shfl_down(s1, off);
    s2 += __shfl_down(s2, off);
    d  += __shfl_down(d, off);
  }
  __shared__ float red[4][3];
  __shared__ float bc[2];
  int wave = t >> 6, lane = t & 63;
  if (lane == 0) { red[wave][0] = s1; red[wave][1] = s2; red[wave][2] = d; }
  __syncthreads();
  if (t == 0) {
    float S1 = red[0][0] + red[1][0] + red[2][0] + red[3][0];
    float S2 = red[0][1] + red[1][1] + red[2][1] + red[3][1];
    float Dd = red[0][2] + red[1][2] + red[2][2] + red[3][2];
    bc[0] = 1.0f / fmaxf(sqrtf(S1), EPS_N);
    bc[1] = 1.0f / fmaxf(sqrtf(S2), EPS_N);
    dots[row] = Dd;
  }
  __syncthreads();
  float sc1 = bc[0], sc2 = bc[1];
  __hip_bfloat16* o1 = fnb + (size_t)row * D_DIM;
  __hip_bfloat16* o2 = fnb + (size_t)(row + B_ROWS) * D_DIM;
  o1[2 * t]     = __float2bfloat16(a.x * sc1);
  o1[2 * t + 1] = __float2bfloat16(a.y * sc1);
  o2[2 * t]     = __float2bfloat16(b.x * sc2);
  o2[2 * t + 1] = __float2bfloat16(b.y * sc2);
}

// ---- kernel 2: swapped-operand MFMA sim + in-register exp-sum/top-5 ----
__global__ __launch_bounds__(256, 3) void sim_kernel(
    const __hip_bfloat16* __restrict__ fnb,
    float* __restrict__ partials)      // [N_ROWS][CSPLIT][6] = sum, top5 (desc)
{
  __shared__ char As[BM * 128];        // 16 KiB: A tile 128 rows x 64 bf16 (swizzled)
  __shared__ char Bs[BN * 128];        // 16 KiB: B tile 128 cols x 64 bf16 (swizzled)

  int bx = blockIdx.x;                 // 0..511
  int rt = bx >> 3, chunk = bx & 7;
  int rowbase = rt * BM;
  int chunkbase = chunk * COLS_PER_CHUNK;

  int t = threadIdx.x;
  int wave = t >> 6, lane = t & 63;
  int wr = wave >> 1, wc = wave & 1;   // 2x2 wave grid, 64x64 per wave
  int l15 = lane & 15, lg = lane >> 4;

  int srow = t >> 3;                   // staging: row = r*32 + (t>>3)
  int scb  = (t & 7) * 16;             // staging col byte 0..112

  float sum[4];
  float top[4][5];
  floatx4 acc[4][4];
  #pragma unroll
  for (int j = 0; j < 4; ++j) {
    sum[j] = 0.f;
    #pragma unroll
    for (int k = 0; k < 5; ++k) top[j][k] = 0.f;
  }

  int myrow[4];
  #pragma unroll
  for (int j = 0; j < 4; ++j) myrow[j] = rowbase + wr * 64 + j * 16 + l15;

  const char* gA  = (const char*)fnb + (size_t)rowbase * 1024;
  const char* gB0 = (const char*)fnb + (size_t)chunkbase * 1024;

  for (int it = 0; it < NIT; ++it) {
    int strip = it >> 3, kstep = it & 7;
    int kb0 = kstep * 128;
    const char* gB = gB0 + (size_t)strip * BN * 1024;

    // issue next tile's global loads early (regs) — latency hides under scan/barrier
    int4 va[4], vb[4];
    #pragma unroll
    for (int r = 0; r < 4; ++r) {
      int row = r * 32 + srow;
      va[r] = *(const int4*)(gA + (size_t)row * 1024 + kb0 + scb);
      vb[r] = *(const int4*)(gB + (size_t)row * 1024 + kb0 + scb);
    }

    if (kstep == 0) {
      if (it > 0) {
        int scanbase = chunkbase + (strip - 1) * BN + wc * 64 + (lg << 2);
        scan_acc(acc, sum, top, myrow, scanbase);
      }
      floatx4 z = {0.f, 0.f, 0.f, 0.f};
      #pragma unroll
      for (int i = 0; i < 4; ++i)
        #pragma unroll
        for (int j = 0; j < 4; ++j)
          acc[i][j] = z;
    }

    __syncthreads();                   // prior frag reads done; LDS free
    #pragma unroll
    for (int r = 0; r < 4; ++r) {
      int row = r * 32 + srow;
      int dst = (row * 128 + scb) ^ ((row & 7) << 4);
      *(int4*)(As + dst) = va[r];
      *(int4*)(Bs + dst) = vb[r];
    }
    __syncthreads();                   // tile visible

    #pragma unroll
    for (int ks = 0; ks < 2; ++ks) {
      int kb = ks * 64 + (lg << 4);
      short8 rf[4], cf[4];
      #pragma unroll
      for (int j = 0; j < 4; ++j) rf[j] = ldsFrag(As, wr * 64 + j * 16 + l15, kb);
      #pragma unroll
      for (int i = 0; i < 4; ++i) cf[i] = ldsFrag(Bs, wc * 64 + i * 16 + l15, kb);
      #pragma unroll
      for (int i = 0; i < 4; ++i)
        #pragma unroll
        for (int j = 0; j < 4; ++j)
          acc[i][j] = __builtin_amdgcn_mfma_f32_16x16x32_bf16(cf[i], rf[j], acc[i][j], 0, 0, 0);
    }
  }

  // scan last strip
  {
    int scanbase = chunkbase + (STRIPS - 1) * BN + wc * 64 + (lg << 2);
    scan_acc(acc, sum, top, myrow, scanbase);
  }

  // merge the 4 lane-groups (disjoint col subsets, same rows) within each wave
  #pragma unroll
  for (int j = 0; j < 4; ++j) {
    #pragma unroll
    for (int m = 16; m <= 32; m <<= 1) {
      sum[j] += __shfl_xor(sum[j], m);
      float pt[5];
      #pragma unroll
      for (int k = 0; k < 5; ++k) pt[k] = __shfl_xor(top[j][k], m);
      #pragma unroll
      for (int k = 0; k < 5; ++k) insert5(top[j], pt[k]);
    }
  }

  // ---- cross-wave merge: wc=0 and wc=1 waves hold disjoint COLUMN halves of
  // the same rows — must be combined before writing partials (R2 bug: ln2 shift)
  float* mbuf = (float*)As;            // [2][2][64][6] = 6 KiB, As is dead
  __syncthreads();                     // all LDS frag reads done
  if (lg == 0) {
    #pragma unroll
    for (int j = 0; j < 4; ++j) {
      float* dst = mbuf + (size_t)(((wr * 2 + wc) * 64) + j * 16 + l15) * 6;
      dst[0] = sum[j];
      #pragma unroll
      for (int k = 0; k < 5; ++k) dst[1 + k] = top[j][k];
    }
  }
  __syncthreads();
  if (t < 128) {
    int wr2 = t >> 6, r = t & 63;
    const float* p0 = mbuf + (size_t)((wr2 * 2 + 0) * 64 + r) * 6;
    const float* p1 = mbuf + (size_t)((wr2 * 2 + 1) * 64 + r) * 6;
    float s = p0[0] + p1[0];
    float a5[5];
    #pragma unroll
    for (int k = 0; k < 5; ++k) a5[k] = p0[1 + k];
    #pragma unroll
    for (int k = 0; k < 5; ++k) insert5(a5, p1[1 + k]);
    int grow = rowbase + wr2 * 64 + r;
    float* dst = partials + ((size_t)grow * CSPLIT + chunk) * 6;
    dst[0] = s;
    #pragma unroll
    for (int k = 0; k < 5; ++k) dst[1 + k] = a5[k];
  }
}

// -------------------- kernel 3a: per-row loss, 32-block partial sums ----------
__global__ __launch_bounds__(256) void finalize1_kernel(
    const float* __restrict__ partials, const float* __restrict__ dots,
    float* __restrict__ bpart)
{
  int row = blockIdx.x * 256 + threadIdx.x;    // 32*256 = 8192
  const float* p = partials + (size_t)row * (CSPLIT * 6);
  float s = 0.0f;
  float a5[5] = {0.f, 0.f, 0.f, 0.f, 0.f};
  #pragma unroll
  for (int c = 0; c < CSPLIT; ++c) {
    s += p[c * 6];
    #pragma unroll
    for (int k = 0; k < 5; ++k) insert5(a5, p[c * 6 + 1 + k]);
  }
  float ng = s - (a5[0] + a5[1] + a5[2] + a5[3] + a5[4]);
  float dv = dots[row & (B_ROWS - 1)];
  float acc = __logf(ng + __expf(dv * INV_T)) - dv * INV_T;

  #pragma unroll
  for (int off = 32; off >= 1; off >>= 1) acc += __shfl_down(acc, off);
  __shared__ float red[4];
  int wave = threadIdx.x >> 6, lane = threadIdx.x & 63;
  if (lane == 0) red[wave] = acc;
  __syncthreads();
  if (threadIdx.x == 0)
    bpart[blockIdx.x] = red[0] + red[1] + red[2] + red[3];
}

// -------------------- kernel 3b: final reduce --------------------
__global__ __launch_bounds__(64) void finalize2_kernel(
    const float* __restrict__ bpart, float* __restrict__ out)
{
  int t = threadIdx.x;
  float v = (t < 32) ? bpart[t] : 0.0f;
  #pragma unroll
  for (int off = 32; off >= 1; off >>= 1) v += __shfl_down(v, off);
  if (t == 0) out[0] = v / (float)N_ROWS;
}

extern "C" void kernel_launch(void* const* d_in, const int* in_sizes, int n_in,
                              void* d_out, int out_size, void* d_ws, size_t ws_size,
                              hipStream_t stream) {
  const float* f1 = (const float*)d_in[0];
  const float* f2 = (const float*)d_in[1];
  float* out = (float*)d_out;
  char* ws = (char*)d_ws;

  __hip_bfloat16* fnb = (__hip_bfloat16*)ws;                          // 8 MiB
  float* dots = (float*)(ws + (size_t)8 * 1024 * 1024);               // 16 KiB
  float* partials = (float*)(ws + (size_t)8 * 1024 * 1024 + 65536);   // 1.5 MiB
  float* bpart = (float*)(ws + (size_t)10 * 1024 * 1024);             // 128 B

  prep_kernel<<<B_ROWS, 256, 0, stream>>>(f1, f2, fnb, dots);
  sim_kernel<<<(N_ROWS / BM) * CSPLIT, 256, 0, stream>>>(fnb, partials);
  finalize1_kernel<<<32, 256, 0, stream>>>(partials, dots, bpart);
  finalize2_kernel<<<1, 64, 0, stream>>>(bpart, out);
}

// Round 4
// 106.836 us; speedup vs baseline: 2.9875x; 2.9875x over previous
//
#include <hip/hip_runtime.h>
#include <hip/hip_bf16.h>

#define B_ROWS 4096
#define D_DIM  512
#define N_ROWS 8192
#define INV_T  20.0f
#define EPS_N  1e-8f
#define CSPLIT 8
#define BM 128                                  // rows per block
#define BN 128                                  // cols per strip
#define COLS_PER_CHUNK (N_ROWS / CSPLIT)        // 1024
#define STRIPS (COLS_PER_CHUNK / BN)            // 8
#define KSTEPS (D_DIM / 64)                     // 8
#define NIT (STRIPS * KSTEPS)                   // 64
#define TILE_BYTES 16384                        // 128 rows x 128 B (K=64 bf16)
#define BUF_BYTES  (2 * TILE_BYTES)             // A + B

typedef __attribute__((ext_vector_type(8))) short short8;
typedef __attribute__((ext_vector_type(4))) float floatx4;

#define AS1C(p) ((const __attribute__((address_space(1))) void*)(p))
#define AS3(p)  ((__attribute__((address_space(3))) void*)(p))

// swizzled LDS frag read: tile row-major [rows][64] bf16 (128 B/row), byte ^= (row&7)<<4
__device__ __forceinline__ short8 ldsFrag(const char* base, int row, int kbyte) {
  int off = (row * 128 + kbyte) ^ ((row & 7) << 4);
  return *(const short8*)(base + off);
}

__device__ __forceinline__ void insert5(float (&t)[5], float v) {
  #pragma unroll
  for (int i = 0; i < 5; ++i) {
    float hi = fmaxf(t[i], v);
    float lo = fminf(t[i], v);
    t[i] = hi;
    v = lo;
  }
}

__device__ __forceinline__ void scan_acc(floatx4 (&acc)[4][4], float (&sum)[4],
                                         float (&top)[4][5], const int (&myrow)[4],
                                         int scanbase) {
  #pragma unroll
  for (int j = 0; j < 4; ++j) {
    #pragma unroll
    for (int i = 0; i < 4; ++i) {
      #pragma unroll
      for (int e = 0; e < 4; ++e) {
        int col = scanbase + i * 16 + e;
        float ev = __expf(acc[i][j][e] * INV_T);
        ev = (col == myrow[j]) ? 0.0f : ev;
        sum[j] += ev;
        insert5(top[j], ev);
      }
    }
  }
}

// async-stage one 128x64 A tile + B tile into LDS buffer (linear dest,
// pre-swizzled source so ds_read-side XOR swizzle sees the right bytes)
__device__ __forceinline__ void stage_tile(const char* gA_it, const char* gB_it,
                                           char* ldsbuf, int wave, int aoff0) {
  #pragma unroll
  for (int q = 0; q < 4; ++q) {
    __builtin_amdgcn_global_load_lds(AS1C(gA_it + aoff0 + q * 8192),
                                     AS3(ldsbuf + wave * 4096 + q * 1024), 16, 0, 0);
    __builtin_amdgcn_global_load_lds(AS1C(gB_it + aoff0 + q * 8192),
                                     AS3(ldsbuf + TILE_BYTES + wave * 4096 + q * 1024), 16, 0, 0);
  }
}

// -------------------- kernel 1: normalize -> bf16, dot(f1,f2) --------------------
__global__ __launch_bounds__(256) void prep_kernel(
    const float* __restrict__ f1, const float* __restrict__ f2,
    __hip_bfloat16* __restrict__ fnb, float* __restrict__ dots)
{
  int row = blockIdx.x;          // 0..4095
  int t = threadIdx.x;           // 256 threads, 2 elems each
  const float* r1 = f1 + (size_t)row * D_DIM;
  const float* r2 = f2 + (size_t)row * D_DIM;
  float2 a = *(const float2*)(r1 + 2 * t);
  float2 b = *(const float2*)(r2 + 2 * t);
  float s1 = a.x * a.x + a.y * a.y;
  float s2 = b.x * b.x + b.y * b.y;
  float d  = a.x * b.x + a.y * b.y;
  #pragma unroll
  for (int off = 32; off >= 1; off >>= 1) {
    s1 += __shfl_down(s1, off);
    s2 += __shfl_down(s2, off);
    d  += __shfl_down(d, off);
  }
  __shared__ float red[4][3];
  __shared__ float bc[2];
  int wave = t >> 6, lane = t & 63;
  if (lane == 0) { red[wave][0] = s1; red[wave][1] = s2; red[wave][2] = d; }
  __syncthreads();
  if (t == 0) {
    float S1 = red[0][0] + red[1][0] + red[2][0] + red[3][0];
    float S2 = red[0][1] + red[1][1] + red[2][1] + red[3][1];
    float Dd = red[0][2] + red[1][2] + red[2][2] + red[3][2];
    bc[0] = 1.0f / fmaxf(sqrtf(S1), EPS_N);
    bc[1] = 1.0f / fmaxf(sqrtf(S2), EPS_N);
    dots[row] = Dd;
  }
  __syncthreads();
  float sc1 = bc[0], sc2 = bc[1];
  __hip_bfloat16* o1 = fnb + (size_t)row * D_DIM;
  __hip_bfloat16* o2 = fnb + (size_t)(row + B_ROWS) * D_DIM;
  o1[2 * t]     = __float2bfloat16(a.x * sc1);
  o1[2 * t + 1] = __float2bfloat16(a.y * sc1);
  o2[2 * t]     = __float2bfloat16(b.x * sc2);
  o2[2 * t + 1] = __float2bfloat16(b.y * sc2);
}

// ---- kernel 2: swapped-operand MFMA sim + in-register exp-sum/top-5 ----
__global__ __launch_bounds__(256, 2) void sim_kernel(
    const __hip_bfloat16* __restrict__ fnb,
    float* __restrict__ partials)      // [N_ROWS][CSPLIT][6] = sum, top5 (desc)
{
  __shared__ int4 lds4[4096];          // 64 KiB = 2 double-buffers of (A+B)
  char* lds = (char*)lds4;

  int bx = blockIdx.x;                 // 0..511
  int rt = bx >> 3, chunk = bx & 7;
  int rowbase = rt * BM;
  int chunkbase = chunk * COLS_PER_CHUNK;

  int t = threadIdx.x;
  int wave = t >> 6, lane = t & 63;
  int wr = wave >> 1, wc = wave & 1;   // 2x2 wave grid, 64x64 per wave
  int l15 = lane & 15, lg = lane >> 4;

  // per-lane pre-swizzled source offset: lane l writes LDS row (l>>3), col (l&7)*16
  // of its 8-row group; fetch global col ((l&7)*16) ^ ((l>>3)<<4) instead.
  int colsw = ((lane & 7) << 4) ^ ((lane >> 3) << 4);
  int aoff0 = (wave * 32 + (lane >> 3)) * 1024 + colsw;   // + q*8192 per instr

  float sum[4];
  float top[4][5];
  floatx4 acc[4][4];
  #pragma unroll
  for (int j = 0; j < 4; ++j) {
    sum[j] = 0.f;
    #pragma unroll
    for (int k = 0; k < 5; ++k) top[j][k] = 0.f;
    floatx4 z = {0.f, 0.f, 0.f, 0.f};
    #pragma unroll
    for (int i = 0; i < 4; ++i) acc[i][j] = z;
  }

  int myrow[4];
  #pragma unroll
  for (int j = 0; j < 4; ++j) myrow[j] = rowbase + wr * 64 + j * 16 + l15;

  const char* gA  = (const char*)fnb + (size_t)rowbase * 1024;
  const char* gB0 = (const char*)fnb + (size_t)chunkbase * 1024;

  // prologue: stage tile 0 into buffer 0
  stage_tile(gA, gB0, lds, wave, aoff0);
  __syncthreads();                     // drains vmcnt -> tile 0 resident

  for (int it = 0; it < NIT; ++it) {
    int strip = it >> 3, kstep = it & 7;
    int cur = it & 1;

    // issue next tile's async loads into the other buffer (latency hides
    // under this tile's MFMA + scan; completed by end-of-iter barrier)
    if (it + 1 < NIT) {
      int nstrip = (it + 1) >> 3, nkstep = (it + 1) & 7;
      stage_tile(gA + nkstep * 128,
                 gB0 + (size_t)nstrip * (BN * 1024) + nkstep * 128,
                 lds + (cur ^ 1) * BUF_BYTES, wave, aoff0);
    }

    const char* As = lds + cur * BUF_BYTES;
    const char* Bs = As + TILE_BYTES;
    #pragma unroll
    for (int ks = 0; ks < 2; ++ks) {
      int kb = ks * 64 + (lg << 4);
      short8 rf[4], cf[4];
      #pragma unroll
      for (int j = 0; j < 4; ++j) rf[j] = ldsFrag(As, wr * 64 + j * 16 + l15, kb);
      #pragma unroll
      for (int i = 0; i < 4; ++i) cf[i] = ldsFrag(Bs, wc * 64 + i * 16 + l15, kb);
      #pragma unroll
      for (int i = 0; i < 4; ++i)
        #pragma unroll
        for (int j = 0; j < 4; ++j)
          acc[i][j] = __builtin_amdgcn_mfma_f32_16x16x32_bf16(cf[i], rf[j], acc[i][j], 0, 0, 0);
    }

    if (kstep == 7) {                  // strip complete: scan + reset acc
      scan_acc(acc, sum, top, myrow, chunkbase + strip * BN + wc * 64 + (lg << 2));
      floatx4 z = {0.f, 0.f, 0.f, 0.f};
      #pragma unroll
      for (int i = 0; i < 4; ++i)
        #pragma unroll
        for (int j = 0; j < 4; ++j)
          acc[i][j] = z;
    }

    __syncthreads();                   // reads of cur done + next tile resident
  }

  // merge the 4 lane-groups (disjoint col subsets, same rows) within each wave
  #pragma unroll
  for (int j = 0; j < 4; ++j) {
    #pragma unroll
    for (int m = 16; m <= 32; m <<= 1) {
      sum[j] += __shfl_xor(sum[j], m);
      float pt[5];
      #pragma unroll
      for (int k = 0; k < 5; ++k) pt[k] = __shfl_xor(top[j][k], m);
      #pragma unroll
      for (int k = 0; k < 5; ++k) insert5(top[j], pt[k]);
    }
  }

  // cross-wave merge: wc=0 / wc=1 hold disjoint column halves of the same rows
  float* mbuf = (float*)lds;           // [2][2][64][6] = 6 KiB, tiles are dead
  if (lg == 0) {
    #pragma unroll
    for (int j = 0; j < 4; ++j) {
      float* dst = mbuf + (size_t)(((wr * 2 + wc) * 64) + j * 16 + l15) * 6;
      dst[0] = sum[j];
      #pragma unroll
      for (int k = 0; k < 5; ++k) dst[1 + k] = top[j][k];
    }
  }
  __syncthreads();
  if (t < 128) {
    int wr2 = t >> 6, r = t & 63;
    const float* p0 = mbuf + (size_t)((wr2 * 2 + 0) * 64 + r) * 6;
    const float* p1 = mbuf + (size_t)((wr2 * 2 + 1) * 64 + r) * 6;
    float s = p0[0] + p1[0];
    float a5[5];
    #pragma unroll
    for (int k = 0; k < 5; ++k) a5[k] = p0[1 + k];
    #pragma unroll
    for (int k = 0; k < 5; ++k) insert5(a5, p1[1 + k]);
    int grow = rowbase + wr2 * 64 + r;
    float* dst = partials + ((size_t)grow * CSPLIT + chunk) * 6;
    dst[0] = s;
    #pragma unroll
    for (int k = 0; k < 5; ++k) dst[1 + k] = a5[k];
  }
}

// -------------------- kernel 3a: per-row loss, 32-block partial sums ----------
__global__ __launch_bounds__(256) void finalize1_kernel(
    const float* __restrict__ partials, const float* __restrict__ dots,
    float* __restrict__ bpart)
{
  int row = blockIdx.x * 256 + threadIdx.x;    // 32*256 = 8192
  const float* p = partials + (size_t)row * (CSPLIT * 6);
  float s = 0.0f;
  float a5[5] = {0.f, 0.f, 0.f, 0.f, 0.f};
  #pragma unroll
  for (int c = 0; c < CSPLIT; ++c) {
    s += p[c * 6];
    #pragma unroll
    for (int k = 0; k < 5; ++k) insert5(a5, p[c * 6 + 1 + k]);
  }
  float ng = s - (a5[0] + a5[1] + a5[2] + a5[3] + a5[4]);
  float dv = dots[row & (B_ROWS - 1)];
  float acc = __logf(ng + __expf(dv * INV_T)) - dv * INV_T;

  #pragma unroll
  for (int off = 32; off >= 1; off >>= 1) acc += __shfl_down(acc, off);
  __shared__ float red[4];
  int wave = threadIdx.x >> 6, lane = threadIdx.x & 63;
  if (lane == 0) red[wave] = acc;
  __syncthreads();
  if (threadIdx.x == 0)
    bpart[blockIdx.x] = red[0] + red[1] + red[2] + red[3];
}

// -------------------- kernel 3b: final reduce --------------------
__global__ __launch_bounds__(64) void finalize2_kernel(
    const float* __restrict__ bpart, float* __restrict__ out)
{
  int t = threadIdx.x;
  float v = (t < 32) ? bpart[t] : 0.0f;
  #pragma unroll
  for (int off = 32; off >= 1; off >>= 1) v += __shfl_down(v, off);
  if (t == 0) out[0] = v / (float)N_ROWS;
}

extern "C" void kernel_launch(void* const* d_in, const int* in_sizes, int n_in,
                              void* d_out, int out_size, void* d_ws, size_t ws_size,
                              hipStream_t stream) {
  const float* f1 = (const float*)d_in[0];
  const float* f2 = (const float*)d_in[1];
  float* out = (float*)d_out;
  char* ws = (char*)d_ws;

  __hip_bfloat16* fnb = (__hip_bfloat16*)ws;                          // 8 MiB
  float* dots = (float*)(ws + (size_t)8 * 1024 * 1024);               // 16 KiB
  float* partials = (float*)(ws + (size_t)8 * 1024 * 1024 + 65536);   // 1.5 MiB
  float* bpart = (float*)(ws + (size_t)10 * 1024 * 1024);             // 128 B

  prep_kernel<<<B_ROWS, 256, 0, stream>>>(f1, f2, fnb, dots);
  sim_kernel<<<(N_ROWS / BM) * CSPLIT, 256, 0, stream>>>(fnb, partials);
  finalize1_kernel<<<32, 256, 0, stream>>>(partials, dots, bpart);
  finalize2_kernel<<<1, 64, 0, stream>>>(bpart, out);
}

// Round 5
// 102.021 us; speedup vs baseline: 3.1286x; 1.0472x over previous
//
#include <hip/hip_runtime.h>
#include <hip/hip_bf16.h>

#define B_ROWS 4096
#define D_DIM  512
#define N_ROWS 8192
#define INV_T  20.0f
#define EPS_N  1e-8f
#define CSPLIT 8
#define BM 256                                  // rows per block
#define BN 256                                  // cols per strip
#define COLS_PER_CHUNK (N_ROWS / CSPLIT)        // 1024
#define STRIPS (COLS_PER_CHUNK / BN)            // 4
#define KSTEPS (D_DIM / 64)                     // 8
#define NIT (STRIPS * KSTEPS)                   // 32
#define TILE_BYTES 32768                        // 256 rows x 128 B (K=64 bf16)
#define BUF_BYTES  (2 * TILE_BYTES)             // A + B

typedef __attribute__((ext_vector_type(8))) short short8;
typedef __attribute__((ext_vector_type(16))) float floatx16;

#define AS1C(p) ((const __attribute__((address_space(1))) void*)(p))
#define AS3(p)  ((__attribute__((address_space(3))) void*)(p))

// swizzled LDS frag read: tile row-major [rows][64 bf16] (128 B/row), byte ^= (row&7)<<4
__device__ __forceinline__ short8 ldsFrag(const char* base, int row, int kbyte) {
  int off = (row * 128 + kbyte) ^ ((row & 7) << 4);
  return *(const short8*)(base + off);
}

__device__ __forceinline__ void insert5(float (&t)[5], float v) {
  #pragma unroll
  for (int i = 0; i < 5; ++i) {
    float hi = fmaxf(t[i], v);
    float lo = fminf(t[i], v);
    t[i] = hi;
    v = lo;
  }
}

// scan one strip's acc: exp-sum + top-5, diag excluded.
// 32x32 C/D layout (swapped operands): sim-row = lane&31 (per rb block),
// sim-col = colbase + cb*32 + (reg&3) + 8*(reg>>2)  (colbase includes 4*(lane>>5))
__device__ __forceinline__ void scan_acc(floatx16 (&acc)[4][2], float (&sum)[4],
                                         float (&top)[4][5], const int (&myrow)[4],
                                         int colbase) {
  #pragma unroll
  for (int rb = 0; rb < 4; ++rb) {
    #pragma unroll
    for (int cb = 0; cb < 2; ++cb) {
      #pragma unroll
      for (int r = 0; r < 16; ++r) {
        int col = colbase + cb * 32 + (r & 3) + 8 * (r >> 2);
        float ev = __expf(acc[rb][cb][r] * INV_T);
        ev = (col == myrow[rb]) ? 0.0f : ev;
        sum[rb] += ev;
        insert5(top[rb], ev);
      }
    }
  }
}

// async-stage one 256x64(K) A tile + B tile into LDS buffer (linear dest,
// pre-swizzled per-lane global source so the ds_read XOR swizzle inverts it)
__device__ __forceinline__ void stage_tile(const char* gA_k, const char* gB_k,
                                           char* buf, int wave, int aoff0) {
  #pragma unroll
  for (int q = 0; q < 4; ++q) {
    __builtin_amdgcn_global_load_lds(AS1C(gA_k + aoff0 + q * 8192),
                                     AS3(buf + wave * 4096 + q * 1024), 16, 0, 0);
    __builtin_amdgcn_global_load_lds(AS1C(gB_k + aoff0 + q * 8192),
                                     AS3(buf + TILE_BYTES + wave * 4096 + q * 1024), 16, 0, 0);
  }
}

// -------------------- kernel 1: normalize -> bf16, dot(f1,f2) --------------------
__global__ __launch_bounds__(256) void prep_kernel(
    const float* __restrict__ f1, const float* __restrict__ f2,
    __hip_bfloat16* __restrict__ fnb, float* __restrict__ dots)
{
  int row = blockIdx.x;          // 0..4095
  int t = threadIdx.x;           // 256 threads, 2 elems each
  const float* r1 = f1 + (size_t)row * D_DIM;
  const float* r2 = f2 + (size_t)row * D_DIM;
  float2 a = *(const float2*)(r1 + 2 * t);
  float2 b = *(const float2*)(r2 + 2 * t);
  float s1 = a.x * a.x + a.y * a.y;
  float s2 = b.x * b.x + b.y * b.y;
  float d  = a.x * b.x + a.y * b.y;
  #pragma unroll
  for (int off = 32; off >= 1; off >>= 1) {
    s1 += __shfl_down(s1, off);
    s2 += __shfl_down(s2, off);
    d  += __shfl_down(d, off);
  }
  __shared__ float red[4][3];
  __shared__ float bc[2];
  int wave = t >> 6, lane = t & 63;
  if (lane == 0) { red[wave][0] = s1; red[wave][1] = s2; red[wave][2] = d; }
  __syncthreads();
  if (t == 0) {
    float S1 = red[0][0] + red[1][0] + red[2][0] + red[3][0];
    float S2 = red[0][1] + red[1][1] + red[2][1] + red[3][1];
    float Dd = red[0][2] + red[1][2] + red[2][2] + red[3][2];
    bc[0] = 1.0f / fmaxf(sqrtf(S1), EPS_N);
    bc[1] = 1.0f / fmaxf(sqrtf(S2), EPS_N);
    dots[row] = Dd;
  }
  __syncthreads();
  float sc1 = bc[0], sc2 = bc[1];
  __hip_bfloat16* o1 = fnb + (size_t)row * D_DIM;
  __hip_bfloat16* o2 = fnb + (size_t)(row + B_ROWS) * D_DIM;
  o1[2 * t]     = __float2bfloat16(a.x * sc1);
  o1[2 * t + 1] = __float2bfloat16(a.y * sc1);
  o2[2 * t]     = __float2bfloat16(b.x * sc2);
  o2[2 * t + 1] = __float2bfloat16(b.y * sc2);
}

// ---- kernel 2: 32x32 swapped-operand MFMA sim + in-register exp-sum/top-5 ----
__global__ __launch_bounds__(512, 2) void sim_kernel(
    const __hip_bfloat16* __restrict__ fnb,
    float* __restrict__ partials)      // [N_ROWS][CSPLIT][6] = sum, top5 (desc)
{
  __shared__ int4 lds4[8192];          // 128 KiB = 2 double-buffers of (A+B)
  char* lds = (char*)lds4;

  // XCD-bijective mapping: XCD (bx&7) owns rowtiles 4x..4x+3 across all chunks
  int bx = blockIdx.x;                 // 0..255
  int xcd = bx & 7, kk = bx >> 3;      // kk: 0..31
  int rt = xcd * 4 + (kk & 3);         // 0..31
  int chunk = kk >> 2;                 // 0..7
  int rowbase = rt * BM;
  int chunkbase = chunk * COLS_PER_CHUNK;

  int t = threadIdx.x;
  int wave = t >> 6, lane = t & 63;
  int wr = wave >> 2, wc = wave & 3;   // 2x4 wave grid; wave tile 128 rows x 64 cols
  int l31 = lane & 31, lh = lane >> 5;

  // staging: lane l writes LDS row (l>>3), col (l&7)*16 of its 8-row group;
  // fetch global col ((l&7)*16) ^ (((l>>3)&7)*16) instead (XOR involution).
  int colsw = ((lane & 7) << 4) ^ (((lane >> 3) & 7) << 4);
  int aoff0 = (wave * 32 + (lane >> 3)) * 1024 + colsw;   // + q*8192 per instr

  float sum[4];
  float top[4][5];
  floatx16 acc[4][2];
  #pragma unroll
  for (int rb = 0; rb < 4; ++rb) {
    sum[rb] = 0.f;
    #pragma unroll
    for (int k = 0; k < 5; ++k) top[rb][k] = 0.f;
    #pragma unroll
    for (int cb = 0; cb < 2; ++cb)
      #pragma unroll
      for (int e = 0; e < 16; ++e) acc[rb][cb][e] = 0.0f;
  }

  int myrow[4];
  #pragma unroll
  for (int rb = 0; rb < 4; ++rb) myrow[rb] = rowbase + wr * 128 + rb * 32 + l31;

  const char* gA  = (const char*)fnb + (size_t)rowbase * 1024;
  const char* gB0 = (const char*)fnb + (size_t)chunkbase * 1024;

  stage_tile(gA, gB0, lds, wave, aoff0);
  __syncthreads();                     // drains vmcnt -> tile 0 resident

  for (int it = 0; it < NIT; ++it) {
    int strip = it >> 3, kstep = it & 7, cur = it & 1;

    if (it + 1 < NIT) {
      int ns = (it + 1) >> 3, nk = (it + 1) & 7;
      stage_tile(gA + nk * 128,
                 gB0 + (size_t)ns * (BN * 1024) + nk * 128,
                 lds + (cur ^ 1) * BUF_BYTES, wave, aoff0);
    }

    const char* As = lds + cur * BUF_BYTES;
    const char* Bs = As + TILE_BYTES;
    #pragma unroll
    for (int ks = 0; ks < 4; ++ks) {
      int kb = ks * 32 + (lh << 4);
      short8 rf[4], cf[2];
      #pragma unroll
      for (int rb = 0; rb < 4; ++rb) rf[rb] = ldsFrag(As, wr * 128 + rb * 32 + l31, kb);
      #pragma unroll
      for (int cb = 0; cb < 2; ++cb) cf[cb] = ldsFrag(Bs, wc * 64 + cb * 32 + l31, kb);
      #pragma unroll
      for (int rb = 0; rb < 4; ++rb)
        #pragma unroll
        for (int cb = 0; cb < 2; ++cb)
          acc[rb][cb] = __builtin_amdgcn_mfma_f32_32x32x16_bf16(cf[cb], rf[rb], acc[rb][cb], 0, 0, 0);
    }

    if (kstep == 7) {                  // strip complete: scan + reset acc
      scan_acc(acc, sum, top, myrow, chunkbase + strip * BN + wc * 64 + 4 * lh);
      #pragma unroll
      for (int rb = 0; rb < 4; ++rb)
        #pragma unroll
        for (int cb = 0; cb < 2; ++cb)
          #pragma unroll
          for (int e = 0; e < 16; ++e) acc[rb][cb][e] = 0.0f;
    }

    __syncthreads();                   // reads of cur done + next tile resident
  }

  // merge lane l <-> l+32 (same sim-rows, disjoint col subsets)
  #pragma unroll
  for (int rb = 0; rb < 4; ++rb) {
    sum[rb] += __shfl_xor(sum[rb], 32);
    float pt[5];
    #pragma unroll
    for (int k = 0; k < 5; ++k) pt[k] = __shfl_xor(top[rb][k], 32);
    #pragma unroll
    for (int k = 0; k < 5; ++k) insert5(top[rb], pt[k]);
  }

  // cross-wave merge: 4 wc-waves hold disjoint col ranges of the same rows
  float* mbuf = (float*)lds;           // [8 waves][4 rb][32 lanes][6] = 24 KiB
  if (lane < 32) {
    #pragma unroll
    for (int rb = 0; rb < 4; ++rb) {
      float* dst = mbuf + (size_t)(((wave * 4 + rb) * 32) + lane) * 6;
      dst[0] = sum[rb];
      #pragma unroll
      for (int k = 0; k < 5; ++k) dst[1 + k] = top[rb][k];
    }
  }
  __syncthreads();
  if (t < 256) {                       // thread t owns block-row t
    int wr2 = t >> 7, rb2 = (t >> 5) & 3, r31 = t & 31;
    float s = 0.0f;
    float a5[5] = {0.f, 0.f, 0.f, 0.f, 0.f};
    #pragma unroll
    for (int wc2 = 0; wc2 < 4; ++wc2) {
      const float* src = mbuf + (size_t)((((wr2 * 4 + wc2) * 4 + rb2) * 32) + r31) * 6;
      s += src[0];
      #pragma unroll
      for (int k = 0; k < 5; ++k) insert5(a5, src[1 + k]);
    }
    int grow = rowbase + t;
    float* dst = partials + ((size_t)grow * CSPLIT + chunk) * 6;
    dst[0] = s;
    #pragma unroll
    for (int k = 0; k < 5; ++k) dst[1 + k] = a5[k];
  }
}

// -------------------- kernel 3a: per-row loss, 32-block partial sums ----------
__global__ __launch_bounds__(256) void finalize1_kernel(
    const float* __restrict__ partials, const float* __restrict__ dots,
    float* __restrict__ bpart)
{
  int row = blockIdx.x * 256 + threadIdx.x;    // 32*256 = 8192
  const float* p = partials + (size_t)row * (CSPLIT * 6);
  float s = 0.0f;
  float a5[5] = {0.f, 0.f, 0.f, 0.f, 0.f};
  #pragma unroll
  for (int c = 0; c < CSPLIT; ++c) {
    s += p[c * 6];
    #pragma unroll
    for (int k = 0; k < 5; ++k) insert5(a5, p[c * 6 + 1 + k]);
  }
  float ng = s - (a5[0] + a5[1] + a5[2] + a5[3] + a5[4]);
  float dv = dots[row & (B_ROWS - 1)];
  float acc = __logf(ng + __expf(dv * INV_T)) - dv * INV_T;

  #pragma unroll
  for (int off = 32; off >= 1; off >>= 1) acc += __shfl_down(acc, off);
  __shared__ float red[4];
  int wave = threadIdx.x >> 6, lane = threadIdx.x & 63;
  if (lane == 0) red[wave] = acc;
  __syncthreads();
  if (threadIdx.x == 0)
    bpart[blockIdx.x] = red[0] + red[1] + red[2] + red[3];
}

// -------------------- kernel 3b: final reduce --------------------
__global__ __launch_bounds__(64) void finalize2_kernel(
    const float* __restrict__ bpart, float* __restrict__ out)
{
  int t = threadIdx.x;
  float v = (t < 32) ? bpart[t] : 0.0f;
  #pragma unroll
  for (int off = 32; off >= 1; off >>= 1) v += __shfl_down(v, off);
  if (t == 0) out[0] = v / (float)N_ROWS;
}

extern "C" void kernel_launch(void* const* d_in, const int* in_sizes, int n_in,
                              void* d_out, int out_size, void* d_ws, size_t ws_size,
                              hipStream_t stream) {
  const float* f1 = (const float*)d_in[0];
  const float* f2 = (const float*)d_in[1];
  float* out = (float*)d_out;
  char* ws = (char*)d_ws;

  __hip_bfloat16* fnb = (__hip_bfloat16*)ws;                          // 8 MiB
  float* dots = (float*)(ws + (size_t)8 * 1024 * 1024);               // 16 KiB
  float* partials = (float*)(ws + (size_t)8 * 1024 * 1024 + 65536);   // 1.5 MiB
  float* bpart = (float*)(ws + (size_t)10 * 1024 * 1024);             // 128 B

  prep_kernel<<<B_ROWS, 256, 0, stream>>>(f1, f2, fnb, dots);
  sim_kernel<<<(N_ROWS / BM) * CSPLIT, 512, 0, stream>>>(fnb, partials);
  finalize1_kernel<<<32, 256, 0, stream>>>(partials, dots, bpart);
  finalize2_kernel<<<1, 64, 0, stream>>>(bpart, out);
}

// Round 6
// 96.294 us; speedup vs baseline: 3.3146x; 1.0595x over previous
//
#include <hip/hip_runtime.h>
#include <hip/hip_bf16.h>

#define B_ROWS 4096
#define D_DIM  512
#define N_ROWS 8192
#define INV_T  20.0f
#define EPS_N  1e-8f
#define CSPLIT 8
#define BM 256                                  // rows per block
#define BN 256                                  // cols per strip
#define COLS_PER_CHUNK (N_ROWS / CSPLIT)        // 1024
#define STRIPS (COLS_PER_CHUNK / BN)            // 4
#define KSTEPS (D_DIM / 64)                     // 8
#define NIT (STRIPS * KSTEPS)                   // 32
#define TILE_BYTES 32768                        // 256 rows x 128 B (K=64 bf16)
#define BUF_BYTES  (2 * TILE_BYTES)             // A + B

typedef __attribute__((ext_vector_type(8))) short short8;
typedef __attribute__((ext_vector_type(16))) float floatx16;

#define AS1C(p) ((const __attribute__((address_space(1))) void*)(p))
#define AS3(p)  ((__attribute__((address_space(3))) void*)(p))

// swizzled LDS frag read: tile row-major [rows][64 bf16] (128 B/row), byte ^= (row&7)<<4
__device__ __forceinline__ short8 ldsFrag(const char* base, int row, int kbyte) {
  int off = (row * 128 + kbyte) ^ ((row & 7) << 4);
  return *(const short8*)(base + off);
}

// sorted-insert via med3: new_t[i] = median(v, t[i], t[i-1]); 5 instrs, all ILP
__device__ __forceinline__ void insert5(float (&t)[5], float v) {
  float n0 = fmaxf(t[0], v);
  float n1 = __builtin_amdgcn_fmed3f(v, t[1], t[0]);
  float n2 = __builtin_amdgcn_fmed3f(v, t[2], t[1]);
  float n3 = __builtin_amdgcn_fmed3f(v, t[3], t[2]);
  float n4 = __builtin_amdgcn_fmed3f(v, t[4], t[3]);
  t[0] = n0; t[1] = n1; t[2] = n2; t[3] = n3; t[4] = n4;
}

// scan one strip: exp-sum + top-5, diag excluded.
// 32x32 C/D (swapped operands): sim-row = lane&31, sim-col = colbase + cb*32 + (r&3) + 8*(r>>2)
__device__ __forceinline__ void scan_acc(floatx16 (&acc)[2][2], float (&sum)[2],
                                         float (&top)[2][5], const int (&myrow)[2],
                                         int colbase) {
  #pragma unroll
  for (int rb = 0; rb < 2; ++rb) {
    #pragma unroll
    for (int cb = 0; cb < 2; ++cb) {
      #pragma unroll
      for (int r = 0; r < 16; ++r) {
        int col = colbase + cb * 32 + (r & 3) + 8 * (r >> 2);
        float ev = __expf(acc[rb][cb][r] * INV_T);
        ev = (col == myrow[rb]) ? 0.0f : ev;
        sum[rb] += ev;
        insert5(top[rb], ev);
      }
    }
  }
}

// stage one 256x64(K) A+B tile pair; 16 waves: waves 0-7 stage A, 8-15 stage B.
// linear LDS dest; per-lane pre-swizzled global source (XOR involution).
__device__ __forceinline__ void stage_tile(const char* gA_k, const char* gB_k,
                                           char* buf, int wave, int aoff0) {
  const char* src = (wave < 8) ? gA_k : gB_k;
  char* dst = buf + ((wave < 8) ? 0 : TILE_BYTES) + (wave & 7) * 4096;
  #pragma unroll
  for (int q = 0; q < 4; ++q) {
    __builtin_amdgcn_global_load_lds(AS1C(src + aoff0 + q * 8192),
                                     AS3(dst + q * 1024), 16, 0, 0);
  }
}

// -------------------- kernel 1: normalize -> bf16, dot(f1,f2) --------------------
__global__ __launch_bounds__(256) void prep_kernel(
    const float* __restrict__ f1, const float* __restrict__ f2,
    __hip_bfloat16* __restrict__ fnb, float* __restrict__ dots)
{
  int row = blockIdx.x;          // 0..4095
  int t = threadIdx.x;           // 256 threads, 2 elems each
  const float* r1 = f1 + (size_t)row * D_DIM;
  const float* r2 = f2 + (size_t)row * D_DIM;
  float2 a = *(const float2*)(r1 + 2 * t);
  float2 b = *(const float2*)(r2 + 2 * t);
  float s1 = a.x * a.x + a.y * a.y;
  float s2 = b.x * b.x + b.y * b.y;
  float d  = a.x * b.x + a.y * b.y;
  #pragma unroll
  for (int off = 32; off >= 1; off >>= 1) {
    s1 += __shfl_down(s1, off);
    s2 += __shfl_down(s2, off);
    d  += __shfl_down(d, off);
  }
  __shared__ float red[4][3];
  __shared__ float bc[2];
  int wave = t >> 6, lane = t & 63;
  if (lane == 0) { red[wave][0] = s1; red[wave][1] = s2; red[wave][2] = d; }
  __syncthreads();
  if (t == 0) {
    float S1 = red[0][0] + red[1][0] + red[2][0] + red[3][0];
    float S2 = red[0][1] + red[1][1] + red[2][1] + red[3][1];
    float Dd = red[0][2] + red[1][2] + red[2][2] + red[3][2];
    bc[0] = 1.0f / fmaxf(sqrtf(S1), EPS_N);
    bc[1] = 1.0f / fmaxf(sqrtf(S2), EPS_N);
    dots[row] = Dd;
  }
  __syncthreads();
  float sc1 = bc[0], sc2 = bc[1];
  __hip_bfloat16* o1 = fnb + (size_t)row * D_DIM;
  __hip_bfloat16* o2 = fnb + (size_t)(row + B_ROWS) * D_DIM;
  o1[2 * t]     = __float2bfloat16(a.x * sc1);
  o1[2 * t + 1] = __float2bfloat16(a.y * sc1);
  o2[2 * t]     = __float2bfloat16(b.x * sc2);
  o2[2 * t + 1] = __float2bfloat16(b.y * sc2);
}

// ---- kernel 2: 32x32 swapped-operand MFMA sim + in-register exp-sum/top-5 ----
// 1024 threads, 4x4 wave grid, wave tile 64x64 -> acc[2][2] (64 AGPR), 4 waves/SIMD
__global__ __launch_bounds__(1024) void sim_kernel(
    const __hip_bfloat16* __restrict__ fnb,
    float* __restrict__ partials)      // [N_ROWS][CSPLIT][6] = sum, top5 (desc)
{
  __shared__ int4 lds4[8192];          // 128 KiB = 2 double-buffers of (A+B)
  char* lds = (char*)lds4;

  // XCD-bijective mapping: XCD (bx&7) owns rowtiles 4x..4x+3 across all chunks
  int bx = blockIdx.x;                 // 0..255
  int xcd = bx & 7, kk = bx >> 3;      // kk: 0..31
  int rt = xcd * 4 + (kk & 3);         // 0..31
  int chunk = kk >> 2;                 // 0..7
  int rowbase = rt * BM;
  int chunkbase = chunk * COLS_PER_CHUNK;

  int t = threadIdx.x;
  int wave = t >> 6, lane = t & 63;
  int wr = wave >> 2, wc = wave & 3;   // 4x4 wave grid; wave tile 64 rows x 64 cols
  int l31 = lane & 31, lh = lane >> 5;

  // staging: lane l writes LDS row (l>>3), col (l&7)*16 of its 8-row group;
  // fetch global col ((l&7)*16) ^ ((l>>3)*16) instead (XOR involution).
  int colsw = ((lane & 7) << 4) ^ ((lane >> 3) << 4);
  int aoff0 = ((wave & 7) * 32 + (lane >> 3)) * 1024 + colsw;   // + q*8192 per instr

  float sum[2];
  float top[2][5];
  floatx16 acc[2][2];
  #pragma unroll
  for (int rb = 0; rb < 2; ++rb) {
    sum[rb] = 0.f;
    #pragma unroll
    for (int k = 0; k < 5; ++k) top[rb][k] = 0.f;
    #pragma unroll
    for (int cb = 0; cb < 2; ++cb)
      #pragma unroll
      for (int e = 0; e < 16; ++e) acc[rb][cb][e] = 0.0f;
  }

  int myrow[2];
  #pragma unroll
  for (int rb = 0; rb < 2; ++rb) myrow[rb] = rowbase + wr * 64 + rb * 32 + l31;

  const char* gA  = (const char*)fnb + (size_t)rowbase * 1024;
  const char* gB0 = (const char*)fnb + (size_t)chunkbase * 1024;

  stage_tile(gA, gB0, lds, wave, aoff0);
  __syncthreads();                     // drains vmcnt -> tile 0 resident

  for (int it = 0; it < NIT; ++it) {
    int strip = it >> 3, kstep = it & 7, cur = it & 1;

    if (it + 1 < NIT) {
      int ns = (it + 1) >> 3, nk = (it + 1) & 7;
      stage_tile(gA + nk * 128,
                 gB0 + (size_t)ns * (BN * 1024) + nk * 128,
                 lds + (cur ^ 1) * BUF_BYTES, wave, aoff0);
    }

    const char* As = lds + cur * BUF_BYTES;
    const char* Bs = As + TILE_BYTES;
    #pragma unroll
    for (int ks = 0; ks < 4; ++ks) {
      int kb = ks * 32 + (lh << 4);
      short8 rf[2], cf[2];
      rf[0] = ldsFrag(As, wr * 64 + l31,      kb);
      rf[1] = ldsFrag(As, wr * 64 + 32 + l31, kb);
      cf[0] = ldsFrag(Bs, wc * 64 + l31,      kb);
      cf[1] = ldsFrag(Bs, wc * 64 + 32 + l31, kb);
      #pragma unroll
      for (int rb = 0; rb < 2; ++rb)
        #pragma unroll
        for (int cb = 0; cb < 2; ++cb)
          acc[rb][cb] = __builtin_amdgcn_mfma_f32_32x32x16_bf16(cf[cb], rf[rb], acc[rb][cb], 0, 0, 0);
    }

    if (kstep == 7) {                  // strip complete: scan + reset acc
      scan_acc(acc, sum, top, myrow, chunkbase + strip * BN + wc * 64 + 4 * lh);
      #pragma unroll
      for (int rb = 0; rb < 2; ++rb)
        #pragma unroll
        for (int cb = 0; cb < 2; ++cb)
          #pragma unroll
          for (int e = 0; e < 16; ++e) acc[rb][cb][e] = 0.0f;
    }

    __syncthreads();                   // reads of cur done + next tile resident
  }

  // merge lane l <-> l+32 (same sim-rows, disjoint col subsets)
  #pragma unroll
  for (int rb = 0; rb < 2; ++rb) {
    sum[rb] += __shfl_xor(sum[rb], 32);
    float pt[5];
    #pragma unroll
    for (int k = 0; k < 5; ++k) pt[k] = __shfl_xor(top[rb][k], 32);
    #pragma unroll
    for (int k = 0; k < 5; ++k) insert5(top[rb], pt[k]);
  }

  // cross-wave merge: 4 wc-waves hold disjoint col ranges of the same rows
  float* mbuf = (float*)lds;           // [16 waves][2 rb][32 lanes][6] = 24 KiB
  if (lane < 32) {
    #pragma unroll
    for (int rb = 0; rb < 2; ++rb) {
      float* dst = mbuf + (size_t)(((wave * 2 + rb) * 32) + lane) * 6;
      dst[0] = sum[rb];
      #pragma unroll
      for (int k = 0; k < 5; ++k) dst[1 + k] = top[rb][k];
    }
  }
  __syncthreads();
  if (t < 256) {                       // thread t owns block-row t
    int wr2 = t >> 6, rb2 = (t >> 5) & 1, r31 = t & 31;
    float s = 0.0f;
    float a5[5] = {0.f, 0.f, 0.f, 0.f, 0.f};
    #pragma unroll
    for (int wc2 = 0; wc2 < 4; ++wc2) {
      int w = wr2 * 4 + wc2;
      const float* src = mbuf + (size_t)(((w * 2 + rb2) * 32) + r31) * 6;
      s += src[0];
      #pragma unroll
      for (int k = 0; k < 5; ++k) insert5(a5, src[1 + k]);
    }
    int grow = rowbase + t;
    float* dst = partials + ((size_t)grow * CSPLIT + chunk) * 6;
    dst[0] = s;
    #pragma unroll
    for (int k = 0; k < 5; ++k) dst[1 + k] = a5[k];
  }
}

// -------------------- kernel 3a: per-row loss, 32-block partial sums ----------
__global__ __launch_bounds__(256) void finalize1_kernel(
    const float* __restrict__ partials, const float* __restrict__ dots,
    float* __restrict__ bpart)
{
  int row = blockIdx.x * 256 + threadIdx.x;    // 32*256 = 8192
  const float* p = partials + (size_t)row * (CSPLIT * 6);
  float s = 0.0f;
  float a5[5] = {0.f, 0.f, 0.f, 0.f, 0.f};
  #pragma unroll
  for (int c = 0; c < CSPLIT; ++c) {
    s += p[c * 6];
    #pragma unroll
    for (int k = 0; k < 5; ++k) insert5(a5, p[c * 6 + 1 + k]);
  }
  float ng = s - (a5[0] + a5[1] + a5[2] + a5[3] + a5[4]);
  float dv = dots[row & (B_ROWS - 1)];
  float acc = __logf(ng + __expf(dv * INV_T)) - dv * INV_T;

  #pragma unroll
  for (int off = 32; off >= 1; off >>= 1) acc += __shfl_down(acc, off);
  __shared__ float red[4];
  int wave = threadIdx.x >> 6, lane = threadIdx.x & 63;
  if (lane == 0) red[wave] = acc;
  __syncthreads();
  if (threadIdx.x == 0)
    bpart[blockIdx.x] = red[0] + red[1] + red[2] + red[3];
}

// -------------------- kernel 3b: final reduce --------------------
__global__ __launch_bounds__(64) void finalize2_kernel(
    const float* __restrict__ bpart, float* __restrict__ out)
{
  int t = threadIdx.x;
  float v = (t < 32) ? bpart[t] : 0.0f;
  #pragma unroll
  for (int off = 32; off >= 1; off >>= 1) v += __shfl_down(v, off);
  if (t == 0) out[0] = v / (float)N_ROWS;
}

extern "C" void kernel_launch(void* const* d_in, const int* in_sizes, int n_in,
                              void* d_out, int out_size, void* d_ws, size_t ws_size,
                              hipStream_t stream) {
  const float* f1 = (const float*)d_in[0];
  const float* f2 = (const float*)d_in[1];
  float* out = (float*)d_out;
  char* ws = (char*)d_ws;

  __hip_bfloat16* fnb = (__hip_bfloat16*)ws;                          // 8 MiB
  float* dots = (float*)(ws + (size_t)8 * 1024 * 1024);               // 16 KiB
  float* partials = (float*)(ws + (size_t)8 * 1024 * 1024 + 65536);   // 1.5 MiB
  float* bpart = (float*)(ws + (size_t)10 * 1024 * 1024);             // 128 B

  prep_kernel<<<B_ROWS, 256, 0, stream>>>(f1, f2, fnb, dots);
  sim_kernel<<<(N_ROWS / BM) * CSPLIT, 1024, 0, stream>>>(fnb, partials);
  finalize1_kernel<<<32, 256, 0, stream>>>(partials, dots, bpart);
  finalize2_kernel<<<1, 64, 0, stream>>>(bpart, out);
}